// Round 5
// baseline (328.814 us; speedup 1.0000x reference)
//
#include <hip/hip_runtime.h>

typedef _Float16 f16;
typedef _Float16 f16x8 __attribute__((ext_vector_type(8)));
typedef float f32x4 __attribute__((ext_vector_type(4)));

#define MFMA16(a, b, c) __builtin_amdgcn_mfma_f32_16x16x32_f16((a), (b), (c), 0, 0, 0)

constexpr int SEQ   = 16;
constexpr int PLEN  = 15;
constexpr int BATCH = 32768;
constexpr int POSE  = 34;
constexpr int HD    = 64;
constexpr int ROWS  = 32;
constexpr int XROW  = 136;   // [h 0..63 | x 64..97 | 1.0 @98 | 0..127 | pad]

constexpr float LOG2E  = 1.4426950408889634f;
constexpr float LOG2E2 = 2.8853900817779268f;

// d_ws byte layout
constexpr size_t OFF_ENC  = 0;         // [256][128] f16 enc W' (bias col @98, log2e-scaled)
constexpr size_t OFF_DEC0 = 65536;     // [256][128] f16 dec W' (original, for decoder step 0)
constexpr size_t OFF_EFF  = 131072;    // [256][64]  f16 W_eff = Whh_d + Wih_d@fc_w (scaled)
constexpr size_t OFF_FCW  = 163840;    // [48][64]   f16 fc_w (rows>=34 zero)
constexpr size_t OFF_BEFF = 169984;    // [256]      f32 b_eff = b_d + Wih_d@fc_b (scaled)

__device__ __forceinline__ float rcpf(float x)   { return __builtin_amdgcn_rcpf(x); }
__device__ __forceinline__ float exp2f_(float x) { return __builtin_amdgcn_exp2f(x); }

// ---------- one-time weight prep: fuse decoder fc feedback + pre-format f16 ----------
__global__ void prep(const float* __restrict__ Wih_e, const float* __restrict__ Whh_e,
                     const float* __restrict__ b_e,
                     const float* __restrict__ Wih_d, const float* __restrict__ Whh_d,
                     const float* __restrict__ b_d,
                     const float* __restrict__ fc_w, const float* __restrict__ fc_b,
                     f16* wEnc, f16* wDec0, f16* wEff, f16* wFc, float* bEff)
{
    const int r = blockIdx.x * 64 + threadIdx.x;   // gate row 0..255
    const float sc = (r >= 128 && r < 192) ? LOG2E2 : LOG2E;   // g-gate rows: 2*log2e

    #pragma unroll 4
    for (int c = 0; c < 128; ++c) {
        float ve = 0.f, vd = 0.f;
        if (c < 64)       { ve = Whh_e[r * 64 + c];        vd = Whh_d[r * 64 + c]; }
        else if (c < 98)  { ve = Wih_e[r * 34 + (c - 64)]; vd = Wih_d[r * 34 + (c - 64)]; }
        else if (c == 98) { ve = b_e[r];                   vd = b_d[r]; }
        wEnc[r * 128 + c]  = (f16)(ve * sc);
        wDec0[r * 128 + c] = (f16)(vd * sc);
    }

    float wih[POSE];
    #pragma unroll
    for (int p = 0; p < POSE; ++p) wih[p] = Wih_d[r * POSE + p];

    for (int k = 0; k < HD; ++k) {
        float acc = Whh_d[r * HD + k];
        #pragma unroll
        for (int p = 0; p < POSE; ++p) acc += wih[p] * fc_w[p * HD + k];
        wEff[r * HD + k] = (f16)(acc * sc);
    }
    float bb = b_d[r];
    #pragma unroll
    for (int p = 0; p < POSE; ++p) bb += wih[p] * fc_b[p];
    bEff[r] = bb * sc;

    if (r < 48) {
        for (int k = 0; k < HD; ++k)
            wFc[r * HD + k] = (f16)((r < POSE) ? fc_w[r * HD + k] : 0.f);
    }
}

// ---------- main fused seq2seq LSTM ----------
__global__ __launch_bounds__(256, 4)
void lstm4(const float* __restrict__ obs,
           const f16* __restrict__ wEnc, const f16* __restrict__ wDec0,
           const f16* __restrict__ wEff, const f16* __restrict__ wFc,
           const float* __restrict__ bEff, const float* __restrict__ fc_b,
           float* __restrict__ out)
{
    __shared__ f16   bfr[2 * ROWS * XROW];     // 17408 B activation double-buffer
    __shared__ float outst[2][ROWS * POSE];    //  8704 B fc-output staging (coalesced flush)

    const int tid  = threadIdx.x;
    const int lane = tid & 63;
    const int q    = tid >> 6;     // gate-column split: j = q*16 + l15
    const int l15  = lane & 15;
    const int l4   = lane >> 4;
    const int blkbase = blockIdx.x * ROWS;

    f16x8 Bw[4][4];   // weight B-frags (enc: 4 kf; dec fused: kf 0..1 reused)
    auto loadB128 = [&](const f16* W) {
        #pragma unroll
        for (int gg = 0; gg < 4; ++gg)
            #pragma unroll
            for (int kf = 0; kf < 4; ++kf)
                Bw[gg][kf] = *(const f16x8*)&W[((gg * 4 + q) * 16 + l15) * 128 + kf * 32 + l4 * 8];
    };
    auto loadB64 = [&](const f16* W) {
        #pragma unroll
        for (int gg = 0; gg < 4; ++gg)
            #pragma unroll
            for (int kf = 0; kf < 2; ++kf)
                Bw[gg][kf] = *(const f16x8*)&W[((gg * 4 + q) * 16 + l15) * 64 + kf * 32 + l4 * 8];
    };

    auto stage_x = [&](int ts, int dstbuf) {
        const float* src = obs + ((size_t)ts * BATCH + blkbase) * POSE;  // contiguous
        #pragma unroll
        for (int it = 0; it < 5; ++it) {
            int i = it * 256 + tid;
            if (i < ROWS * POSE) {
                int row = i / POSE, col = i - row * POSE;
                bfr[(dstbuf * ROWS + row) * XROW + HD + col] = (f16)src[i];
            }
        }
    };

    // fc frags + biases (register-resident, one-time)
    const int  p    = q * 16 + l15;
    const bool fcok = (q < 3);
    f16x8 Bfc[2];
    #pragma unroll
    for (int kf = 0; kf < 2; ++kf)
        Bfc[kf] = fcok ? *(const f16x8*)&wFc[p * HD + kf * 32 + l4 * 8] : (f16x8)(f16)0.f;
    const float fcb = (fcok && p < POSE) ? fc_b[p] : 0.f;
    float be[4];
    #pragma unroll
    for (int gg = 0; gg < 4; ++gg) be[gg] = bEff[(gg * 4 + q) * 16 + l15];

    loadB128(wEnc);

    // init activation buffers: h0 = 0, bias col = 1.0
    for (int i = tid; i < 2 * ROWS * XROW; i += 256) {
        int c = i % XROW;
        bfr[i] = (c == 98) ? (f16)1.0f : (f16)0.0f;
    }
    __syncthreads();
    stage_x(0, 0);
    __syncthreads();

    f32x4 cst[2];
    cst[0] = (f32x4)0.f;
    cst[1] = (f32x4)0.f;

    // nonlin: consumes acc (pre-scaled by log2e / 2log2e), updates cst, writes h to buf
    auto nonlin = [&](f32x4 (&acc)[2][4], int dstbuf) {
        #pragma unroll
        for (int mf = 0; mf < 2; ++mf) {
            #pragma unroll
            for (int r = 0; r < 4; ++r) {
                float si = rcpf(1.f + exp2f_(-acc[mf][0][r]));
                float sf = rcpf(1.f + exp2f_(-acc[mf][1][r]));
                float tg = 1.f - 2.f * rcpf(1.f + exp2f_(acc[mf][2][r]));
                float so = rcpf(1.f + exp2f_(-acc[mf][3][r]));
                float c  = sf * cst[mf][r] + si * tg;
                float tc = 1.f - 2.f * rcpf(1.f + exp2f_(c * LOG2E2));
                cst[mf][r] = c;
                bfr[(dstbuf * ROWS + mf * 16 + l4 * 4 + r) * XROW + q * 16 + l15] = (f16)(so * tc);
            }
        }
    };

    auto fc_to_stage = [&](int srcbuf, int sbuf) {  // fc(h) -> outst[sbuf]
        if (!fcok) return;
        f16x8 ah[2][2];
        #pragma unroll
        for (int mf = 0; mf < 2; ++mf)
            #pragma unroll
            for (int kf = 0; kf < 2; ++kf)
                ah[mf][kf] = *(const f16x8*)&bfr[(srcbuf * ROWS + mf * 16 + l15) * XROW + kf * 32 + l4 * 8];
        f32x4 o0 = {fcb, fcb, fcb, fcb}, o1 = {fcb, fcb, fcb, fcb};
        #pragma unroll
        for (int kf = 0; kf < 2; ++kf) {
            o0 = MFMA16(ah[0][kf], Bfc[kf], o0);
            o1 = MFMA16(ah[1][kf], Bfc[kf], o1);
        }
        if (p < POSE) {
            #pragma unroll
            for (int r = 0; r < 4; ++r) {
                outst[sbuf][(l4 * 4 + r) * POSE + p]      = o0[r];
                outst[sbuf][(16 + l4 * 4 + r) * POSE + p] = o1[r];
            }
        }
    };

    auto flush_out = [&](int t, int sbuf) {  // coalesced block-wide f32 store
        float* ob = out + ((size_t)t * BATCH + blkbase) * POSE;
        const float* st = outst[sbuf];
        for (int j = tid; j < ROWS * POSE; j += 256) ob[j] = st[j];
    };

    int cur = 0;

    // ======== encoder: 16 steps, 1 barrier each ========
    #pragma unroll 1
    for (int s = 0; s < SEQ; ++s) {
        const int nxt = cur ^ 1;
        f16x8 a[2][4];
        #pragma unroll
        for (int mf = 0; mf < 2; ++mf)
            #pragma unroll
            for (int kf = 0; kf < 4; ++kf)
                a[mf][kf] = *(const f16x8*)&bfr[(cur * ROWS + mf * 16 + l15) * XROW + kf * 32 + l4 * 8];
        { int ts = s + 1 < 15 ? s + 1 : 15; stage_x(ts, nxt); }

        f32x4 acc[2][4];
        #pragma unroll
        for (int mf = 0; mf < 2; ++mf)
            #pragma unroll
            for (int gg = 0; gg < 4; ++gg) acc[mf][gg] = (f32x4)0.f;
        #pragma unroll
        for (int kf = 0; kf < 4; ++kf)
            #pragma unroll
            for (int gg = 0; gg < 4; ++gg) {
                acc[0][gg] = MFMA16(a[0][kf], Bw[gg][kf], acc[0][gg]);
                acc[1][gg] = MFMA16(a[1][kf], Bw[gg][kf], acc[1][gg]);
            }
        nonlin(acc, nxt);
        __syncthreads();
        cur = nxt;
    }

    // ======== decoder step 0: original weights, x = obs[15] (already staged) ========
    loadB128(wDec0);
    {
        const int nxt = cur ^ 1;
        f16x8 a[2][4];
        #pragma unroll
        for (int mf = 0; mf < 2; ++mf)
            #pragma unroll
            for (int kf = 0; kf < 4; ++kf)
                a[mf][kf] = *(const f16x8*)&bfr[(cur * ROWS + mf * 16 + l15) * XROW + kf * 32 + l4 * 8];
        f32x4 acc[2][4];
        #pragma unroll
        for (int mf = 0; mf < 2; ++mf)
            #pragma unroll
            for (int gg = 0; gg < 4; ++gg) acc[mf][gg] = (f32x4)0.f;
        #pragma unroll
        for (int kf = 0; kf < 4; ++kf)
            #pragma unroll
            for (int gg = 0; gg < 4; ++gg) {
                acc[0][gg] = MFMA16(a[0][kf], Bw[gg][kf], acc[0][gg]);
                acc[1][gg] = MFMA16(a[1][kf], Bw[gg][kf], acc[1][gg]);
            }
        nonlin(acc, nxt);
        __syncthreads();
        fc_to_stage(nxt, 0);     // out t=0
        cur = nxt;
    }
    loadB64(wEff);   // switch to fused decoder weights (K=64, bias via be[])

    // ======== decoder steps 1..14: fused recurrence, 1 barrier/step ========
    #pragma unroll 1
    for (int t = 1; t < PLEN; ++t) {
        const int nxt = cur ^ 1;
        f16x8 a[2][2];
        #pragma unroll
        for (int mf = 0; mf < 2; ++mf)
            #pragma unroll
            for (int kf = 0; kf < 2; ++kf)
                a[mf][kf] = *(const f16x8*)&bfr[(cur * ROWS + mf * 16 + l15) * XROW + kf * 32 + l4 * 8];

        f32x4 acc[2][4];
        #pragma unroll
        for (int mf = 0; mf < 2; ++mf)
            #pragma unroll
            for (int gg = 0; gg < 4; ++gg) acc[mf][gg] = (f32x4){be[gg], be[gg], be[gg], be[gg]};
        #pragma unroll
        for (int kf = 0; kf < 2; ++kf)
            #pragma unroll
            for (int gg = 0; gg < 4; ++gg) {
                acc[0][gg] = MFMA16(a[0][kf], Bw[gg][kf], acc[0][gg]);
                acc[1][gg] = MFMA16(a[1][kf], Bw[gg][kf], acc[1][gg]);
            }
        nonlin(acc, nxt);
        __syncthreads();
        flush_out(t - 1, (t - 1) & 1);   // coalesced store of previous step's output
        fc_to_stage(nxt, t & 1);         // this step's fc -> staging
        cur = nxt;
    }
    __syncthreads();
    flush_out(PLEN - 1, (PLEN - 1) & 1);
}

extern "C" void kernel_launch(void* const* d_in, const int* in_sizes, int n_in,
                              void* d_out, int out_size, void* d_ws, size_t ws_size,
                              hipStream_t stream) {
    const float* obs   = (const float*)d_in[0];
    const float* Wih_e = (const float*)d_in[1];
    const float* Whh_e = (const float*)d_in[2];
    const float* b_e   = (const float*)d_in[3];
    const float* Wih_d = (const float*)d_in[4];
    const float* Whh_d = (const float*)d_in[5];
    const float* b_d   = (const float*)d_in[6];
    const float* fc_w  = (const float*)d_in[7];
    const float* fc_b  = (const float*)d_in[8];
    float* out = (float*)d_out;

    char* ws = (char*)d_ws;
    f16*   wEnc  = (f16*)(ws + OFF_ENC);
    f16*   wDec0 = (f16*)(ws + OFF_DEC0);
    f16*   wEff  = (f16*)(ws + OFF_EFF);
    f16*   wFc   = (f16*)(ws + OFF_FCW);
    float* bEff  = (float*)(ws + OFF_BEFF);

    prep<<<dim3(4), dim3(64), 0, stream>>>(Wih_e, Whh_e, b_e, Wih_d, Whh_d, b_d,
                                           fc_w, fc_b, wEnc, wDec0, wEff, wFc, bEff);
    lstm4<<<dim3(BATCH / ROWS), dim3(256), 0, stream>>>(
        obs, wEnc, wDec0, wEff, wFc, bEff, fc_b, out);
}

// Round 6
// 128.228 us; speedup vs baseline: 2.5643x; 2.5643x over previous
//
#include <hip/hip_runtime.h>

typedef _Float16 f16;
typedef _Float16 f16x8 __attribute__((ext_vector_type(8)));
typedef float f32x4 __attribute__((ext_vector_type(4)));

#define MFMA16(a, b, c) __builtin_amdgcn_mfma_f32_16x16x32_f16((a), (b), (c), 0, 0, 0)

constexpr int SEQ   = 16;
constexpr int PLEN  = 15;
constexpr int BATCH = 32768;
constexpr int POSE  = 34;
constexpr int HD    = 64;
constexpr int GRPS  = 2;     // two independent 32-row chains per wave (in-wave ILP)
constexpr int ROWS  = 32;    // rows per group
constexpr int BROWS = GRPS * ROWS;  // 64 rows per block
constexpr int XROW  = 136;   // [h 0..63 | x 64..97 | 1.0 @98 | 0..127 | pad]

constexpr float LOG2E  = 1.4426950408889634f;
constexpr float LOG2E2 = 2.8853900817779268f;

__device__ __forceinline__ float rcpf(float x)   { return __builtin_amdgcn_rcpf(x); }
__device__ __forceinline__ float exp2f_(float x) { return __builtin_amdgcn_exp2f(x); }

__global__ __launch_bounds__(256, 2)
void lstm6(const float* __restrict__ obs,
           const float* __restrict__ Wih_e, const float* __restrict__ Whh_e,
           const float* __restrict__ b_e,
           const float* __restrict__ Wih_d, const float* __restrict__ Whh_d,
           const float* __restrict__ b_d,
           const float* __restrict__ fc_w, const float* __restrict__ fc_b,
           float* __restrict__ out)
{
    // [dbuf][grp][row][XROW] activation rows — 34816 B
    __shared__ f16 bfr[2 * GRPS * ROWS * XROW];

    const int tid  = threadIdx.x;
    const int lane = tid & 63;
    const int q    = tid >> 6;     // gate-column split: j = q*16 + l15
    const int l15  = lane & 15;
    const int l4   = lane >> 4;
    const int blkbase = blockIdx.x * BROWS;

    // ---- weight B-frags directly from global f32 (R4 path; no d_ws) ----
    f16x8 Bw[4][4];
    auto loadB = [&](const float* __restrict__ Wih, const float* __restrict__ Whh,
                     const float* __restrict__ b) {
        #pragma unroll
        for (int gg = 0; gg < 4; ++gg) {
            const int r = (gg * 4 + q) * 16 + l15;
            const float sc = (gg == 2) ? LOG2E2 : LOG2E;
            #pragma unroll
            for (int kf = 0; kf < 2; ++kf) {
                const float* src = Whh + r * HD + kf * 32 + l4 * 8;
                #pragma unroll
                for (int j = 0; j < 8; ++j) Bw[gg][kf][j] = (f16)(src[j] * sc);
            }
            {
                const float* src = Wih + r * POSE + l4 * 8;
                #pragma unroll
                for (int j = 0; j < 8; ++j) Bw[gg][2][j] = (f16)(src[j] * sc);
            }
            #pragma unroll
            for (int j = 0; j < 8; ++j) {
                const int k = 96 + l4 * 8 + j;
                float v = 0.f;
                if (k < 98)       v = Wih[r * POSE + (k - 64)];
                else if (k == 98) v = b[r];
                Bw[gg][3][j] = (f16)(v * sc);
            }
        }
    };
    loadB(Wih_e, Whh_e, b_e);

    auto stage_x = [&](int ts, int dstbuf) {
        const float* src = obs + ((size_t)ts * BATCH + blkbase) * POSE;  // 2176 contiguous f32
        #pragma unroll
        for (int it = 0; it < 9; ++it) {
            int i = it * 256 + tid;
            if (i < BROWS * POSE) {
                int row = i / POSE, col = i - row * POSE;
                bfr[((dstbuf * GRPS + (row >> 5)) * ROWS + (row & 31)) * XROW + HD + col] = (f16)src[i];
            }
        }
    };

    // fc weights / bias, register-resident
    const int  p    = q * 16 + l15;
    const bool fcok = (q < 3);
    f16x8 Bfc[2];
    #pragma unroll
    for (int kf = 0; kf < 2; ++kf)
        #pragma unroll
        for (int j = 0; j < 8; ++j)
            Bfc[kf][j] = (f16)((fcok && p < POSE) ? fc_w[p * HD + kf * 32 + l4 * 8 + j] : 0.f);
    const float fcb = (fcok && p < POSE) ? fc_b[p] : 0.f;

    // init: h0 = 0, bias col = 1.0
    for (int i = tid; i < 2 * GRPS * ROWS * XROW; i += 256) {
        int c = i % XROW;
        bfr[i] = (c == 98) ? (f16)1.0f : (f16)0.0f;
    }
    __syncthreads();
    stage_x(0, 0);
    __syncthreads();

    f32x4 cst[GRPS][2];   // per-group cell state
    #pragma unroll
    for (int g = 0; g < GRPS; ++g) { cst[g][0] = (f32x4)0.f; cst[g][1] = (f32x4)0.f; }

    auto ldA = [&](int grp, int srcbuf, f16x8 (&a)[2][4]) {
        #pragma unroll
        for (int mf = 0; mf < 2; ++mf)
            #pragma unroll
            for (int kf = 0; kf < 4; ++kf)
                a[mf][kf] = *(const f16x8*)&bfr[((srcbuf * GRPS + grp) * ROWS + mf * 16 + l15) * XROW + kf * 32 + l4 * 8];
    };
    auto gates = [&](const f16x8 (&a)[2][4], f32x4 (&acc)[2][4]) {
        #pragma unroll
        for (int mf = 0; mf < 2; ++mf)
            #pragma unroll
            for (int gg = 0; gg < 4; ++gg) acc[mf][gg] = (f32x4)0.f;
        #pragma unroll
        for (int kf = 0; kf < 4; ++kf)
            #pragma unroll
            for (int gg = 0; gg < 4; ++gg) {
                acc[0][gg] = MFMA16(a[0][kf], Bw[gg][kf], acc[0][gg]);
                acc[1][gg] = MFMA16(a[1][kf], Bw[gg][kf], acc[1][gg]);
            }
    };
    auto nonlin = [&](int grp, f32x4 (&acc)[2][4], int dstbuf) {
        #pragma unroll
        for (int mf = 0; mf < 2; ++mf) {
            #pragma unroll
            for (int r = 0; r < 4; ++r) {
                float si = rcpf(1.f + exp2f_(-acc[mf][0][r]));
                float sf = rcpf(1.f + exp2f_(-acc[mf][1][r]));
                float tg = 1.f - 2.f * rcpf(1.f + exp2f_(acc[mf][2][r]));
                float so = rcpf(1.f + exp2f_(-acc[mf][3][r]));
                float c  = sf * cst[grp][mf][r] + si * tg;
                float tc = 1.f - 2.f * rcpf(1.f + exp2f_(c * LOG2E2));
                cst[grp][mf][r] = c;
                bfr[((dstbuf * GRPS + grp) * ROWS + mf * 16 + l4 * 4 + r) * XROW + q * 16 + l15] = (f16)(so * tc);
            }
        }
    };
    auto fc_step = [&](int grp, int srcbuf, int t) {
        if (!fcok) return;
        f16x8 ah[2][2];
        #pragma unroll
        for (int mf = 0; mf < 2; ++mf)
            #pragma unroll
            for (int kf = 0; kf < 2; ++kf)
                ah[mf][kf] = *(const f16x8*)&bfr[((srcbuf * GRPS + grp) * ROWS + mf * 16 + l15) * XROW + kf * 32 + l4 * 8];
        f32x4 o0 = {fcb, fcb, fcb, fcb}, o1 = {fcb, fcb, fcb, fcb};
        #pragma unroll
        for (int kf = 0; kf < 2; ++kf) {
            o0 = MFMA16(ah[0][kf], Bfc[kf], o0);
            o1 = MFMA16(ah[1][kf], Bfc[kf], o1);
        }
        if (p < POSE) {
            float* ob = out + ((size_t)t * BATCH + blkbase + grp * ROWS) * POSE;
            #pragma unroll
            for (int r = 0; r < 4; ++r) {
                int r0 = l4 * 4 + r, r1 = 16 + l4 * 4 + r;
                ob[r0 * POSE + p] = o0[r];
                ob[r1 * POSE + p] = o1[r];
                bfr[((srcbuf * GRPS + grp) * ROWS + r0) * XROW + HD + p] = (f16)o0[r];  // feedback
                bfr[((srcbuf * GRPS + grp) * ROWS + r1) * XROW + HD + p] = (f16)o1[r];
            }
        }
    };

    int cur = 0;

    // ======== encoder: 16 steps, 1 barrier each, 2 chains interleaved ========
    #pragma unroll 1
    for (int s = 0; s < SEQ; ++s) {
        const int nxt = cur ^ 1;
        f16x8 aA[2][4], aB[2][4];
        f32x4 accA[2][4], accB[2][4];
        ldA(0, cur, aA);
        gates(aA, accA);
        ldA(1, cur, aB);
        gates(aB, accB);              // independent of nonlin(0) — overlaps its trans chain
        { int ts = s + 1 < 15 ? s + 1 : 15; stage_x(ts, nxt); }
        nonlin(0, accA, nxt);
        nonlin(1, accB, nxt);
        __syncthreads();
        cur = nxt;
    }

    // ======== decoder: 15 steps (R4 structure, per group) ========
    loadB(Wih_d, Whh_d, b_d);
    #pragma unroll 1
    for (int t = 0; t < PLEN; ++t) {
        const int nxt = cur ^ 1;
        f16x8 aA[2][4], aB[2][4];
        f32x4 accA[2][4], accB[2][4];
        ldA(0, cur, aA);
        gates(aA, accA);
        ldA(1, cur, aB);
        gates(aB, accB);
        nonlin(0, accA, nxt);
        nonlin(1, accB, nxt);
        __syncthreads();              // h complete -> fc reads full 64-wide h
        fc_step(0, nxt, t);           // writes out + x-feedback into buf[nxt]
        fc_step(1, nxt, t);
        __syncthreads();              // feedback visible before next step's A-reads
        cur = nxt;
    }
}

extern "C" void kernel_launch(void* const* d_in, const int* in_sizes, int n_in,
                              void* d_out, int out_size, void* d_ws, size_t ws_size,
                              hipStream_t stream) {
    const float* obs   = (const float*)d_in[0];
    const float* Wih_e = (const float*)d_in[1];
    const float* Whh_e = (const float*)d_in[2];
    const float* b_e   = (const float*)d_in[3];
    const float* Wih_d = (const float*)d_in[4];
    const float* Whh_d = (const float*)d_in[5];
    const float* b_d   = (const float*)d_in[6];
    const float* fc_w  = (const float*)d_in[7];
    const float* fc_b  = (const float*)d_in[8];
    float* out = (float*)d_out;

    lstm6<<<dim3(BATCH / BROWS), dim3(256), 0, stream>>>(
        obs, Wih_e, Whh_e, b_e, Wih_d, Whh_d, b_d, fc_w, fc_b, out);
}